// Round 16
// baseline (97.983 us; speedup 1.0000x reference)
//
#include <hip/hip_runtime.h>
#include <float.h>

#define NSEG 8
#define SEGLEN 1024   // B*Ls*H*D = 1*4*8*32
#define BIGV 1e30f    // "infinity" for invalid DP cells
#define PADV 1e18f    // x-pad sentinel: huge cost, no overflow over a chunk

#define NW 4          // waves per block (256 threads); wave owns 256 cols
#define CH 64         // steps per chunk (one flag handshake per chunk)
#define NCH 17        // local steps 0..1087 (lane 63 hits row 1023 at t=1086)
#define XLEN 1152     // xl[t] = x[t] for t<1024, else PADV (read up to 1087)
#define BSTRIDE 1160  // bnd[w][r+64] = D[r, 256w-1]; max read index 1152

#define DPPF(OLD, SRC, CTRL, RM, BM, BC)                                      \
    __int_as_float(__builtin_amdgcn_update_dpp(                               \
        __float_as_int(OLD), __float_as_int(SRC), CTRL, RM, BM, BC))
// lane i <- lane i-1; lane 0 <- OLD[lane 0]   (validated R2-R15)
#define WSHIFT1(OLD, SRC) DPPF(OLD, SRC, 0x138, 0xF, 0xF, false)

__device__ __forceinline__ float readlaneF(float v, int l) {
    return __int_as_float(__builtin_amdgcn_readlane(__float_as_int(v), l));
}

// Lane-skewed systolic DTW, 4 waves (1 per SIMD). Wave w owns cols
// [256w,256w+256); lane L owns c_e = 256w+4L+e, e in 0..3.
// At local step t, lane L computes ROW r = t - L of its four columns.
// R16a: cells use the min-plus scan identity (R13's algebra, numerically
// validated there; its perf regression was the WSTREAM DPP streams, which
// are NOT used here -- injects stay R15's group-hoisted readlanes):
//   ls_e = cumsum |x-y_e|;  a0 = min(P0,dgl);  a_e = min(P_e,P_{e-1})-ls_{e-1}
//   r0 = min(a0, lf); r_e = min(r_{e-1}, a_e);  P_e' = ls_e + r_e
// lf-critical chain = 7 ops (vs 13 for the d-form min3 chain); ls/a terms
// are off-chain. Expected issue-bound ~26 inst/step.
// R16b: softmax+output epilogue FUSED via last-block ticket (fence +
// device-scope atomicAdd; the block drawing ticket 63 computes d_out).
// Rows r<0 / r>1023 compute garbage >= ~1e18 acting as +inf (never selected
// by real cells; garbage boundary rows feed only garbage rows).
// Cross-wave boundary: lane 63 writes D[r,256w+255] to bnd[w+1][r+64] each
// step (others hit a dump sink, branchless); monotone chunk-counter
// handshake with lag 2 (consumer chunk tc reads rows <= 64tc+64).
__global__ __launch_bounds__(256) void dtw_sk4_kernel(const float* __restrict__ q,
                                                      const float* __restrict__ kk,
                                                      const float* __restrict__ vv,
                                                      float* __restrict__ out,
                                                      float* __restrict__ dists,
                                                      int* __restrict__ cnt) {
    __shared__ float xl[XLEN];
    __shared__ float bnd[NW + 1][BSTRIDE];  // bnd[0] = BIGV region for wave 0
    __shared__ float dump[128];             // sink, indices up to 125 (R8 lesson)
    __shared__ int flagsA[NW + 1];          // [0]=sentinel; [w+1]=wave w chunks done
    __shared__ int lastFlag;
    __shared__ float wgt[NSEG][NSEG];       // epilogue softmax weights
    const int tid = threadIdx.x;
    const int lane = tid & 63;
    const int wv = tid >> 6;
    const int pair = blockIdx.x;            // 0..63
    const float* __restrict__ x = q + (pair >> 3) * SEGLEN;
    const float* __restrict__ y = kk + (pair & 7) * SEGLEN;

    for (int t = tid; t < XLEN; t += 256) xl[t] = (t < SEGLEN) ? x[t] : PADV;
    // flat index 63 = bnd[0][63] = virtual corner D[-1,-1] = 0; rest BIGV.
    for (int t = tid; t < (NW + 1) * BSTRIDE; t += 256)
        (&bnd[0][0])[t] = (t == 63) ? 0.f : BIGV;
    if (tid < NW + 1) flagsA[tid] = (tid == 0) ? 0x7FFFFFFF : 0;
    if (tid == 0) lastFlag = 0;

    const float4 y4 = *(const float4*)(y + wv * 256 + lane * 4);
    const float yv0 = y4.x, yv1 = y4.y, yv2 = y4.z, yv3 = y4.w;

    __syncthreads();   // the only barrier before the main loop

    const float* __restrict__ br = &bnd[wv][0];   // left neighbor's boundary

    // wait for the first 2 producer chunks before reading init boundary
    {
        const int need0 = (NCH < 2) ? NCH : 2;
        while (__hip_atomic_load(&flagsA[wv], __ATOMIC_ACQUIRE,
                                 __HIP_MEMORY_SCOPE_WORKGROUP) < need0)
            __builtin_amdgcn_s_sleep(1);
    }
    float P0 = BIGV, P1 = BIGV, P2 = BIGV, P3 = BIGV, xreg = PADV;
    float lf = br[64];    // D[0, 256w-1] (wave 0: BIGV); real only for lane 0
    float dgl = br[63];   // D[-1,256w-1] (wave 0: corner 0)

// One systolic step with pre-hoisted inject values xp (x) and bp (boundary).
#define STEP(s, xp, bp) {                                                     \
    xreg = WSHIFT1(xp, xreg);                                                 \
    const float ls0 = fabsf(xreg - yv0);                                      \
    const float ls1 = ls0 + fabsf(xreg - yv1);                                \
    const float ls2 = ls1 + fabsf(xreg - yv2);                                \
    const float ls3 = ls2 + fabsf(xreg - yv3);                                \
    const float a0 = fminf(P0, dgl);                                          \
    const float a1 = fminf(P1, P0) - ls0;                                     \
    const float a2 = fminf(P2, P1) - ls1;                                     \
    const float a3 = fminf(P3, P2) - ls2;                                     \
    const float r0 = fminf(a0, lf);                                           \
    const float r1 = fminf(r0, a1);                                           \
    const float r2 = fminf(r1, a2);                                           \
    const float r3 = fminf(r2, a3);                                           \
    P0 = ls0 + r0; P1 = ls1 + r1; P2 = ls2 + r2; P3 = ls3 + r3;               \
    const float n1 = WSHIFT1(bp, P3);                                         \
    dgl = lf; lf = n1;                                                        \
    va[(s)] = P3;                                                             \
}
// 8-step group: hoist all 16 readlanes to the top so the SGPR hazards and
// s->v movs amortize and schedule away from the dependent DPPs (R15 win).
#define STEP8(s) {                                                            \
    const float xp0 = readlaneF(xv, (s)+0), xp1 = readlaneF(xv, (s)+1);       \
    const float xp2 = readlaneF(xv, (s)+2), xp3 = readlaneF(xv, (s)+3);       \
    const float xp4 = readlaneF(xv, (s)+4), xp5 = readlaneF(xv, (s)+5);       \
    const float xp6 = readlaneF(xv, (s)+6), xp7 = readlaneF(xv, (s)+7);       \
    const float bp0 = readlaneF(bvv, (s)+0), bp1 = readlaneF(bvv, (s)+1);     \
    const float bp2 = readlaneF(bvv, (s)+2), bp3 = readlaneF(bvv, (s)+3);     \
    const float bp4 = readlaneF(bvv, (s)+4), bp5 = readlaneF(bvv, (s)+5);     \
    const float bp6 = readlaneF(bvv, (s)+6), bp7 = readlaneF(bvv, (s)+7);     \
    STEP((s)+0, xp0, bp0) STEP((s)+1, xp1, bp1)                               \
    STEP((s)+2, xp2, bp2) STEP((s)+3, xp3, bp3)                               \
    STEP((s)+4, xp4, bp4) STEP((s)+5, xp5, bp5)                               \
    STEP((s)+6, xp6, bp6) STEP((s)+7, xp7, bp7)                               \
}

#pragma unroll 1
    for (int tc = 0; tc < NCH; ++tc) {
        // consumer chunk tc reads bnd rows <= 64tc+64 (index 64tc+128);
        // producer writes row r at its step r+63 -> needs chunk tc+1 done
        // (flag >= tc+2), capped at NCH (later indices are BIGV pad).
        const int need = (tc + 2 < NCH) ? (tc + 2) : NCH;
        while (__hip_atomic_load(&flagsA[wv], __ATOMIC_ACQUIRE,
                                 __HIP_MEMORY_SCOPE_WORKGROUP) < need)
            __builtin_amdgcn_s_sleep(1);

        const float xv = xl[CH * tc + lane];         // x[64tc+s] inject stream
        const float bvv = br[CH * tc + 65 + lane];   // inject: bnd row 64tc+s+1
        // boundary write: lane 63 -> bnd[wv+1][64tc+1+s]; others -> dump
        float* va = (lane == 63) ? &bnd[wv + 1][CH * tc + 1] : &dump[lane];

        STEP8(0) STEP8(8) STEP8(16) STEP8(24) STEP8(32) STEP8(40) STEP8(48) STEP8(56)

        // publish chunk tc (release orders the ds_writes above before the flag)
        __hip_atomic_store(&flagsA[wv + 1], tc + 1, __ATOMIC_RELEASE,
                           __HIP_MEMORY_SCOPE_WORKGROUP);
    }
#undef STEP
#undef STEP8

    // D[1023,1023]: wave 3 lane 63 col e=3 at t=1086 -> bnd[NW][1087]
    // (t=1087 overwrites P3 with a garbage row, so read back from LDS).
    // Same thread publishes the ticket (store -> fence -> atomicAdd).
    if (wv == NW - 1 && lane == 0) {
        dists[pair] = bnd[NW][1087];
        __threadfence();   // make dists visible device-wide before the ticket
        int old = __hip_atomic_fetch_add(cnt, 1, __ATOMIC_ACQ_REL,
                                         __HIP_MEMORY_SCOPE_AGENT);
        if (old == NSEG * NSEG - 1) lastFlag = 1;   // this block runs epilogue
    }
    __syncthreads();
    if (!lastFlag) return;

    // ---- fused epilogue (one block): softmax rows, then weighted sum ----
    if (tid < NSEG) {
        float l[NSEG], mx = -FLT_MAX;
#pragma unroll
        for (int j = 0; j < NSEG; ++j) {
            l[j] = 0.5f * dists[tid * NSEG + j];
            mx = fmaxf(mx, l[j]);
        }
        float s = 0.f;
#pragma unroll
        for (int j = 0; j < NSEG; ++j) { l[j] = expf(l[j] - mx); s += l[j]; }
        const float inv = 1.f / s;
#pragma unroll
        for (int j = 0; j < NSEG; ++j) wgt[tid][j] = l[j] * inv;
    }
    __syncthreads();
    for (int o = tid; o < NSEG * SEGLEN; o += 256) {
        const int i = o >> 10;
        const int p = o & 1023;
        float acc = 0.f;
#pragma unroll
        for (int j = 0; j < NSEG; ++j) acc += wgt[i][j] * vv[j * SEGLEN + p];
        out[o] = acc;
    }
}

extern "C" void kernel_launch(void* const* d_in, const int* in_sizes, int n_in,
                              void* d_out, int out_size, void* d_ws, size_t ws_size,
                              hipStream_t stream) {
    const float* q = (const float*)d_in[0];   // queries [1,32,8,32] f32
    const float* k = (const float*)d_in[1];   // keys
    const float* v = (const float*)d_in[2];   // values
    float* out = (float*)d_out;               // [8192] f32
    float* dists = (float*)d_ws;              // 64 floats scratch
    int* cnt = (int*)((char*)d_ws + 256);     // completion ticket counter

    hipMemsetAsync(cnt, 0, sizeof(int), stream);
    dtw_sk4_kernel<<<dim3(NSEG * NSEG), dim3(256), 0, stream>>>(q, k, v, out,
                                                                dists, cnt);
}

// Round 18
// 70.778 us; speedup vs baseline: 1.3844x; 1.3844x over previous
//
#include <hip/hip_runtime.h>
#include <float.h>

#define NSEG 8
#define SEGLEN 1024   // B*Ls*H*D = 1*4*8*32
#define BIGV 1e30f    // "infinity" for invalid DP cells
#define PADV 1e18f    // x-pad sentinel: huge cost; garbage stays < 1e21

#define NW 4          // waves per block (256 threads); wave owns 256 cols
#define CHD 32        // double-steps per chunk (64 rows per chunk)
#define NCHD 18       // double-steps k = 0..575 (lane63 hits rows 1022/1023 at k=574)
#define XLEN 1152     // xl[t] = x[t] for t<1024, else PADV (read up to 1151)
#define BOFF 128      // bnd[w][row + 128]; lane-63 garbage rows reach -126
#define BSTRIDE 1288  // max read index 64*17+BOFF+2+63 = 1281; write max 1153

#define DPPF(OLD, SRC, CTRL, RM, BM, BC)                                      \
    __int_as_float(__builtin_amdgcn_update_dpp(                               \
        __float_as_int(OLD), __float_as_int(SRC), CTRL, RM, BM, BC))
// lane i <- lane i-1; lane 0 <- OLD[lane 0]   (validated R2-R16)
#define WSHIFT1(OLD, SRC) DPPF(OLD, SRC, 0x138, 0xF, 0xF, false)

__device__ __forceinline__ float readlaneF(float v, int l) {
    return __int_as_float(__builtin_amdgcn_readlane(__float_as_int(v), l));
}

// Lane-skewed systolic DTW, RS=2 (two rows per step), 4 waves (1 per SIMD).
// Wave w owns cols [256w,256w+256); lane L owns c_e = 256w+4L+e, e in 0..3.
// At double-step k, lane L computes rows r0 = 2k-2L and r1 = r0+1 (skew 2/lane;
// lane L-1 -- two rows ahead -- produced rows r0,r1 of col c0-1 LAST step;
// both arrive via two end-of-step wf_sr1 DPPs of its ce3/co3). Cells (d-form):
//   even row: ce_0 = |xe-y0| + min3(Q0, lfe, dgl); ce_e = |xe-y_e| + min3(Q_e, ce_{e-1}, Q_{e-1})
//   odd  row: co_0 = |xo-y0| + min3(ce_0, lfo, lfe); co_e = |xo-y_e| + min3(ce_e, co_{e-1}, ce_{e-1})
// Q = previous step's odd cells (row r0-1); lfe/lfo = left col rows r0/r1;
// dgl = left col row r0-1 (= previous lfo).
// R17 bug (fixed): the boundary inject prepped at step s is consumed at step
// s+1 (lane 0 row 64tc+2s+2) -> bv must lead by +2: br[64tc+BOFF+2+lane]
// (R17 had +0 -> left values 2 rows stale -> absmax 0.97). R12's RS=1 analog
// had the +1 lead (br[...+65+lane]). BSTRIDE bumped 1280->1288 (read 1281).
// x streams via xe/xo systolic registers (inject x[2k]/x[2k+1] at lane 0 from
// group-hoisted readlanes -- R15 win). Garbage rows (r<0, r>1023) carry
// PADV-scale costs acting as +inf. Lane 63 ds_write_b64 {ce3,co3} to
// bnd[w+1][r0+BOFF] (others hit a float2 dump sink). Monotone chunk-counter
// handshake: consumer chunk tc reads rows <= 64tc+65 -> producer chunk tc+2
// done -> flag >= tc+3 (capped at NCHD; later rows = BIGV pad).
__global__ __launch_bounds__(256) void dtw_rs2_kernel(const float* __restrict__ q,
                                                      const float* __restrict__ kk,
                                                      float* __restrict__ dists) {
    __shared__ float xl[XLEN];
    __shared__ float bnd[NW + 1][BSTRIDE];  // bnd[0] = BIGV region for wave 0
    __shared__ float2 dumpf2[96];           // sink: lane + s <= 93
    __shared__ int flagsA[NW + 1];          // [0]=sentinel; [w+1]=wave w chunks done
    const int tid = threadIdx.x;
    const int lane = tid & 63;
    const int wv = tid >> 6;
    const int pair = blockIdx.x;            // 0..63
    const float* __restrict__ x = q + (pair >> 3) * SEGLEN;
    const float* __restrict__ y = kk + (pair & 7) * SEGLEN;

    for (int t = tid; t < XLEN; t += 256) xl[t] = (t < SEGLEN) ? x[t] : PADV;
    // flat index 127 = bnd[0][127] = virtual corner D[-1,-1] = 0; rest BIGV.
    for (int t = tid; t < (NW + 1) * BSTRIDE; t += 256)
        (&bnd[0][0])[t] = (t == BOFF - 1) ? 0.f : BIGV;
    if (tid < NW + 1) flagsA[tid] = (tid == 0) ? 0x7FFFFFFF : 0;

    const float4 y4 = *(const float4*)(y + wv * 256 + lane * 4);
    const float yv0 = y4.x, yv1 = y4.y, yv2 = y4.z, yv3 = y4.w;

    __syncthreads();   // the only block-wide barrier

    const float* __restrict__ br = &bnd[wv][0];   // left neighbor's boundary

    // wait for the first 2 producer chunks (rows -1,0,1 written in chunk 1)
    {
        const int need0 = (NCHD < 2) ? NCHD : 2;
        while (__hip_atomic_load(&flagsA[wv], __ATOMIC_ACQUIRE,
                                 __HIP_MEMORY_SCOPE_WORKGROUP) < need0)
            __builtin_amdgcn_s_sleep(1);
    }
    float Q0 = BIGV, Q1 = BIGV, Q2 = BIGV, Q3 = BIGV;  // row r0-1 of own cols
    float xe = PADV, xo = PADV;
    float lfe = br[BOFF];      // D[0, 256w-1] (wave 0: BIGV); real only lane 0
    float lfo = br[BOFF + 1];  // D[1, 256w-1]
    float dgl = br[BOFF - 1];  // D[-1,256w-1] (wave 0: corner 0)

// One double-step with pre-hoisted inject values.
#define DSTEP(s, xpe, xpo, bpe, bpo) {                                        \
    xe = WSHIFT1(xpe, xe);                                                    \
    xo = WSHIFT1(xpo, xo);                                                    \
    const float ce0 = fabsf(xe - yv0) + fminf(fminf(Q0, lfe), dgl);           \
    const float ce1 = fabsf(xe - yv1) + fminf(fminf(Q1, ce0), Q0);            \
    const float ce2 = fabsf(xe - yv2) + fminf(fminf(Q2, ce1), Q1);            \
    const float ce3 = fabsf(xe - yv3) + fminf(fminf(Q3, ce2), Q2);            \
    const float co0 = fabsf(xo - yv0) + fminf(fminf(ce0, lfo), lfe);          \
    const float co1 = fabsf(xo - yv1) + fminf(fminf(ce1, co0), ce0);          \
    const float co2 = fabsf(xo - yv2) + fminf(fminf(ce2, co1), ce1);          \
    const float co3 = fabsf(xo - yv3) + fminf(fminf(ce3, co2), ce2);          \
    const float n1e = WSHIFT1(bpe, ce3);                                      \
    const float n1o = WSHIFT1(bpo, co3);                                      \
    dgl = lfo; lfe = n1e; lfo = n1o;                                          \
    Q0 = co0; Q1 = co1; Q2 = co2; Q3 = co3;                                   \
    va[(s)] = make_float2(ce3, co3);                                          \
}
// 4-double-step group: hoist all 16 readlanes to the top (R15 win).
#define DSTEP4(s) {                                                           \
    const float xe0 = readlaneF(xv, 2*(s)+0), xo0 = readlaneF(xv, 2*(s)+1);   \
    const float xe1 = readlaneF(xv, 2*(s)+2), xo1 = readlaneF(xv, 2*(s)+3);   \
    const float xe2 = readlaneF(xv, 2*(s)+4), xo2 = readlaneF(xv, 2*(s)+5);   \
    const float xe3 = readlaneF(xv, 2*(s)+6), xo3 = readlaneF(xv, 2*(s)+7);   \
    const float be0 = readlaneF(bv, 2*(s)+0), bo0 = readlaneF(bv, 2*(s)+1);   \
    const float be1 = readlaneF(bv, 2*(s)+2), bo1 = readlaneF(bv, 2*(s)+3);   \
    const float be2 = readlaneF(bv, 2*(s)+4), bo2 = readlaneF(bv, 2*(s)+5);   \
    const float be3 = readlaneF(bv, 2*(s)+6), bo3 = readlaneF(bv, 2*(s)+7);   \
    DSTEP((s)+0, xe0, xo0, be0, bo0) DSTEP((s)+1, xe1, xo1, be1, bo1)         \
    DSTEP((s)+2, xe2, xo2, be2, bo2) DSTEP((s)+3, xe3, xo3, be3, bo3)         \
}

#pragma unroll 1
    for (int tc = 0; tc < NCHD; ++tc) {
        // consumer chunk tc reads rows <= 64tc+65; producer chunk tc+2 covers
        // rows <= 64(tc+2)-63 = 64tc+65 -> flag >= tc+3, capped at NCHD.
        const int need = (tc + 3 < NCHD) ? (tc + 3) : NCHD;
        while (__hip_atomic_load(&flagsA[wv], __ATOMIC_ACQUIRE,
                                 __HIP_MEMORY_SCOPE_WORKGROUP) < need)
            __builtin_amdgcn_s_sleep(1);

        const float xv = xl[64 * tc + lane];              // x[64tc + j] at lane j
        const float bv = br[64 * tc + BOFF + 2 + lane];   // bnd row 64tc+2+j (+2 lead)
        // boundary write: lane 63 -> bnd[wv+1][64tc+2+2s] (= rows r0,r1);
        // others -> dump. r0 = 64tc + 2s - 126 -> index r0+BOFF = 64tc+2+2s.
        float2* va = (lane == 63) ? (float2*)&bnd[wv + 1][64 * tc + 2]
                                  : dumpf2 + lane;

        DSTEP4(0)  DSTEP4(4)  DSTEP4(8)  DSTEP4(12)
        DSTEP4(16) DSTEP4(20) DSTEP4(24) DSTEP4(28)

        // publish chunk tc (release orders the ds_writes above before the flag)
        __hip_atomic_store(&flagsA[wv + 1], tc + 1, __ATOMIC_RELEASE,
                           __HIP_MEMORY_SCOPE_WORKGROUP);
    }
#undef DSTEP
#undef DSTEP4

    // D[1023,1023]: wave 3 lane 63 col e=3, odd row of k=574 (chunk 17, s=30)
    // -> co3 -> bnd[NW][1023+BOFF] = bnd[NW][1151]; read back from LDS.
    if (wv == NW - 1 && lane == 0) dists[pair] = bnd[NW][1151];
}

// out[i*1024+p] = sum_j softmax_j(0.5*dists[i,:])[j] * values[j*1024+p]
__global__ __launch_bounds__(256) void softmax_out_kernel(const float* __restrict__ v,
                                                          const float* __restrict__ dists,
                                                          float* __restrict__ out) {
    const int o = blockIdx.x * blockDim.x + threadIdx.x;
    if (o >= NSEG * SEGLEN) return;
    const int i = o >> 10;
    const int p = o & 1023;

    float l[NSEG];
    float mx = -FLT_MAX;
#pragma unroll
    for (int j = 0; j < NSEG; ++j) {
        l[j] = 0.5f * dists[i * NSEG + j];
        mx = fmaxf(mx, l[j]);
    }
    float s = 0.f;
#pragma unroll
    for (int j = 0; j < NSEG; ++j) {
        l[j] = expf(l[j] - mx);
        s += l[j];
    }
    const float inv = 1.f / s;
    float acc = 0.f;
#pragma unroll
    for (int j = 0; j < NSEG; ++j) acc += (l[j] * inv) * v[j * SEGLEN + p];
    out[o] = acc;
}

extern "C" void kernel_launch(void* const* d_in, const int* in_sizes, int n_in,
                              void* d_out, int out_size, void* d_ws, size_t ws_size,
                              hipStream_t stream) {
    const float* q = (const float*)d_in[0];   // queries [1,32,8,32] f32
    const float* k = (const float*)d_in[1];   // keys
    const float* v = (const float*)d_in[2];   // values
    float* out = (float*)d_out;               // [8192] f32
    float* dists = (float*)d_ws;              // 64 floats scratch

    dtw_rs2_kernel<<<dim3(NSEG * NSEG), dim3(256), 0, stream>>>(q, k, dists);
    softmax_out_kernel<<<dim3((NSEG * SEGLEN + 255) / 256), dim3(256), 0, stream>>>(v, dists, out);
}